// Round 17
// baseline (307.164 us; speedup 1.0000x reference)
//
#include <hip/hip_runtime.h>
#include <hip/hip_bf16.h>

typedef __attribute__((ext_vector_type(8))) short bf16x8;
typedef __attribute__((ext_vector_type(4))) float f32x4;
typedef __attribute__((ext_vector_type(16))) float f32x16;
typedef __attribute__((ext_vector_type(4))) int int4v;

// Problem constants
#define NB 4
#define NN 4096
#define NC 256
#define NSPLIT 4
#define KEYS_PER_SPLIT 1024
#define KT_ITERS 16      // KEYS_PER_SPLIT / 64
#define LOG2E 1.4426950408889634f

__device__ __forceinline__ unsigned short f2bf(float f) {
    unsigned u = __builtin_bit_cast(unsigned, f);
    u += 0x7fffu + ((u >> 16) & 1u);   // round-to-nearest-even
    return (unsigned short)(u >> 16);
}
__device__ __forceinline__ float bf2f(unsigned short u) {
    unsigned v = ((unsigned)u) << 16;
    return __builtin_bit_cast(float, v);
}
__device__ __forceinline__ void load_lds16(const void* g, void* l) {
    __builtin_amdgcn_global_load_lds(
        (const __attribute__((address_space(1))) void*)g,
        (__attribute__((address_space(3))) void*)l, 16, 0, 0);
}
__device__ __forceinline__ unsigned cvtpk(float lo, float hi) {
    unsigned d;
    asm("v_cvt_pk_bf16_f32 %0, %1, %2" : "=v"(d) : "v"(lo), "v"(hi));
    return d;
}
__device__ __forceinline__ void pl32swap(unsigned &a, unsigned &b) {
    asm volatile("v_permlane32_swap_b32 %0, %1" : "+v"(a), "+v"(b));
}
__device__ __forceinline__ float fexp2(float x) {
    float r;
    asm("v_exp_f32 %0, %1" : "=v"(r) : "v"(x));
    return r;
}
__device__ __forceinline__ float frcp(float x) {
    float r;
    asm("v_rcp_f32 %0, %1" : "=v"(r) : "v"(x));
    return r;
}

// ---------------- kernel 0: weight transpose + bf16 cast (+ counter zero) ----------------
// wk is pre-scaled by log2(e) so attention can use v_exp_f32 (2^x) directly.
__global__ __launch_bounds__(256) void wt_kernel(
    const float* __restrict__ wq, const float* __restrict__ wk,
    const float* __restrict__ wv, unsigned short* __restrict__ wt,
    int* __restrict__ counters)
{
    const int c = blockIdx.x;     // 0..319
    const int k = threadIdx.x;    // 0..255
    if (c == 0 && k < 128) counters[k] = 0;   // split-K tile counters, re-zeroed every launch
    float v;
    if (c < 32)      v = wq[k * 32 + c];
    else if (c < 64) v = wk[k * 32 + (c - 32)] * LOG2E;
    else             v = wv[k * 256 + (c - 64)];
    wt[c * 256 + k] = f2bf(v);
}

// ---------------- kernel 1: QKV projection (MFMA, no LDS) ----------------
__global__ __launch_bounds__(256) void proj_kernel(
    const float* __restrict__ x,              // [16384][256]
    const unsigned short* __restrict__ wt,    // [320][256] = W^T bf16
    const float* __restrict__ bq, const float* __restrict__ bk,
    const float* __restrict__ bv,
    unsigned short* __restrict__ q_ws,
    unsigned short* __restrict__ k_ws,
    unsigned short* __restrict__ vt_ws)
{
    const int lane = threadIdx.x & 63;
    const int w    = threadIdx.x >> 6;
    const int l15  = lane & 15, hh = lane >> 4;
    const int m0   = blockIdx.x * 16;      // 16 rows per block
    const int ct0  = w * 5;                // this wave's 5 col-groups

    f32x4 acc[5];
    #pragma unroll
    for (int i = 0; i < 5; ++i) acc[i] = f32x4{0.f, 0.f, 0.f, 0.f};

    const float* xrow = x + (size_t)(m0 + l15) * 256 + hh * 8;
    #pragma unroll
    for (int ks = 0; ks < 8; ++ks) {
        float4 xa = ((const float4*)(xrow + ks * 32))[0];
        float4 xb = ((const float4*)(xrow + ks * 32))[1];
        bf16x8 afrag;
        afrag[0] = (short)f2bf(xa.x); afrag[1] = (short)f2bf(xa.y);
        afrag[2] = (short)f2bf(xa.z); afrag[3] = (short)f2bf(xa.w);
        afrag[4] = (short)f2bf(xb.x); afrag[5] = (short)f2bf(xb.y);
        afrag[6] = (short)f2bf(xb.z); afrag[7] = (short)f2bf(xb.w);
        #pragma unroll
        for (int c = 0; c < 5; ++c) {
            bf16x8 bfrag = *(const bf16x8*)(wt + (size_t)((ct0 + c) * 16 + l15) * 256 + ks * 32 + hh * 8);
            acc[c] = __builtin_amdgcn_mfma_f32_16x16x32_bf16(afrag, bfrag, acc[c], 0, 0, 0);
        }
    }

    const int b    = m0 >> 12;
    const int nloc = m0 & 4095;
    #pragma unroll
    for (int c = 0; c < 5; ++c) {
        const int ct = ct0 + c;
        const int c0 = ct * 16;
        float bias;
        if (c0 < 32)      bias = bq[c0 + l15];
        else if (c0 < 64) bias = bk[c0 - 32 + l15] * LOG2E;
        else              bias = bv[c0 - 64 + l15];
        if (c0 < 64) {
            unsigned short* dst = (c0 < 32) ? q_ws : k_ws;
            const int cc = (c0 < 32) ? c0 : (c0 - 32);
            #pragma unroll
            for (int i = 0; i < 4; ++i)
                dst[(size_t)(m0 + hh * 4 + i) * 32 + cc + l15] = f2bf(acc[c][i] + bias);
        } else {
            const int cc = c0 - 64 + l15;
            #pragma unroll
            for (int i = 0; i < 4; i += 2) {
                unsigned lo = f2bf(acc[c][i]     + bias);
                unsigned hi = f2bf(acc[c][i + 1] + bias);
                *(unsigned*)(vt_ws + ((size_t)b * 256 + cc) * 4096 + nloc + hh * 4 + i)
                    = lo | (hi << 16);
            }
        }
    }
}

// ---------------- kernel 2: flash attention + fused split-K combine tail ----------------
// Main loop: EXACT R14 body (65.3us proven). After the partial-epilogue, each
// block increments a per-(b,qtile) device counter; the LAST of the 4 split
// blocks combines the 128 rows (sum opart/lpart, normalize, + residual) and
// writes the final output. No spinning -> no deadlock; combine overlaps attn.
__global__ __launch_bounds__(512, 4) void attn_kernel(
    const unsigned short* __restrict__ q_ws,
    const unsigned short* __restrict__ k_ws,
    const unsigned short* __restrict__ vt_ws,
    unsigned short* __restrict__ opart,   // [4][16384][256] bf16 (unnormalized)
    float* __restrict__ lpart,            // [4][16384] f32
    const float* __restrict__ x,
    const float* __restrict__ gamma_p,
    float* __restrict__ out,
    int* __restrict__ counters)           // [128] per-(b,qtile) finish counters
{
    __shared__ unsigned short vt_lds[2 * 256 * 64];  // 64 KB, two 32KB buffers
    __shared__ int lastflag;

    const int tid  = threadIdx.x;
    const int lane = tid & 63;
    const int wid  = tid >> 6;     // 0..7
    const int l31  = lane & 31;
    const int hi   = lane >> 5;
    const int wr   = wid >> 1;             // q group (32 rows), 0..3
    const int wc   = wid & 1;              // col half (128 cols)

    // XCD-aware decomposition
    const int xcd   = blockIdx.x & 7;
    const int j     = blockIdx.x >> 3;          // 0..63
    const int combo = xcd * 2 + (j >> 5);       // 0..15
    const int qtile = j & 31;
    const int split = combo >> 2;
    const int b     = combo & 3;
    const int q0    = qtile * 128;
    const int key0  = split * KEYS_PER_SPLIT;

    // persistent Q B-frags
    bf16x8 aq[2];
    #pragma unroll
    for (int cs = 0; cs < 2; ++cs)
        aq[cs] = *(const bf16x8*)(q_ws +
            (size_t)(b * 4096 + q0 + wr * 32 + l31) * 32 + cs * 16 + hi * 8);

    f32x16 acc[4];
    #pragma unroll
    for (int ct = 0; ct < 4; ++ct)
        #pragma unroll
        for (int r = 0; r < 16; ++r) acc[ct][r] = 0.f;
    float lsum = 0.f;

    const unsigned short* vt_base = vt_ws + (size_t)b * 256 * 4096;
    const unsigned short* k_base  = k_ws + (size_t)b * 4096 * 32;

    // ---- prologue: stage tile 0 into buffer 0 ----
    #pragma unroll
    for (int e = 0; e < 4; ++e) {
        int idx  = e * 512 + tid;
        int c    = idx >> 3;
        int slot = idx & 7;
        const unsigned short* src = vt_base + (size_t)c * 4096 + key0 + ((slot ^ (c & 7)) << 3);
        load_lds16(src, (char*)vt_lds + idx * 16);
    }

    for (int kt = 0; kt < KT_ITERS; ++kt) {
        const int kb      = key0 + kt * 64;
        const int cur_off = (kt & 1) << 15;     // byte offset of current V buffer

        // single barrier: STAGE(kt) drained+visible; PV(kt-1) done with other buf
        __syncthreads();

        // ---- prefetch STAGE(kt+1) into the other buffer ----
        if (kt + 1 < KT_ITERS) {
            const int nxt_off = cur_off ^ 32768;
            #pragma unroll
            for (int e = 0; e < 4; ++e) {
                int idx  = e * 512 + tid;
                int c    = idx >> 3;
                int slot = idx & 7;
                const unsigned short* src = vt_base + (size_t)c * 4096 + (kb + 64) + ((slot ^ (c & 7)) << 3);
                load_lds16(src, (char*)vt_lds + nxt_off + idx * 16);
            }
        }

        // ---- swapped QK per 32-key tile + exp2 + in-register P assembly ----
        unsigned pa[4][4];   // [kstep16][dword]
        #pragma unroll
        for (int ktile = 0; ktile < 2; ++ktile) {
            bf16x8 ak0 = *(const bf16x8*)(k_base +
                (size_t)(kb + ktile * 32 + l31) * 32 + hi * 8);
            bf16x8 ak1 = *(const bf16x8*)(k_base +
                (size_t)(kb + ktile * 32 + l31) * 32 + 16 + hi * 8);
            f32x16 e0;
            #pragma unroll
            for (int r = 0; r < 16; ++r) e0[r] = 0.f;
            e0 = __builtin_amdgcn_mfma_f32_32x32x16_bf16(ak0, aq[0], e0, 0, 0, 0);
            e0 = __builtin_amdgcn_mfma_f32_32x32x16_bf16(ak1, aq[1], e0, 0, 0, 0);

            float s = 0.f;
            #pragma unroll
            for (int h = 0; h < 2; ++h) {
                float p0 = fexp2(e0[h*8+0]), p1 = fexp2(e0[h*8+1]);
                float p2 = fexp2(e0[h*8+2]), p3 = fexp2(e0[h*8+3]);
                float p4 = fexp2(e0[h*8+4]), p5 = fexp2(e0[h*8+5]);
                float p6 = fexp2(e0[h*8+6]), p7 = fexp2(e0[h*8+7]);
                s += ((p0 + p1) + (p2 + p3)) + ((p4 + p5) + (p6 + p7));
                unsigned d0 = cvtpk(p0, p1);
                unsigned d1 = cvtpk(p2, p3);
                unsigned d2 = cvtpk(p4, p5);
                unsigned d3 = cvtpk(p6, p7);
                pl32swap(d0, d2);
                pl32swap(d1, d3);
                const int ks = ktile * 2 + h;
                pa[ks][0] = d0; pa[ks][1] = d1;
                pa[ks][2] = d2; pa[ks][3] = d3;
            }
            lsum += s;
        }

        // ---- PV from current buffer (staged last iter, drained at barrier) ----
        __builtin_amdgcn_s_setprio(1);
        #pragma unroll
        for (int ks = 0; ks < 4; ++ks) {
            union { unsigned u[4]; bf16x8 v; } cvt;
            cvt.u[0] = pa[ks][0]; cvt.u[1] = pa[ks][1];
            cvt.u[2] = pa[ks][2]; cvt.u[3] = pa[ks][3];
            #pragma unroll
            for (int ct = 0; ct < 4; ++ct) {
                int c = wc * 128 + ct * 32 + l31;
                int chunk = ks * 2 + hi;
                bf16x8 bvf = *(const bf16x8*)((char*)vt_lds + cur_off + c * 128 + ((chunk ^ (c & 7)) << 4));
                acc[ct] = __builtin_amdgcn_mfma_f32_32x32x16_bf16(cvt.v, bvf, acc[ct], 0, 0, 0);
            }
        }
        __builtin_amdgcn_s_setprio(0);
    }

    // ---- l totals (keys split across hi halves only) ----
    lsum += __shfl_xor(lsum, 32);

    const size_t rowb = (size_t)(split * 4 + b) * 4096 + q0 + wr * 32;
    if (wc == 0 && hi == 0)
        lpart[rowb + l31] = lsum;

    // ---- partial epilogue: direct scalar stores (conflict-free, proven) ----
    #pragma unroll
    for (int ct = 0; ct < 4; ++ct) {
        int col = wc * 128 + ct * 32 + l31;
        #pragma unroll
        for (int rr = 0; rr < 16; ++rr) {
            int row = (rr & 3) + 8 * (rr >> 2) + 4 * hi;
            opart[(rowb + row) * 256 + col] = f2bf(acc[ct][rr]);
        }
    }

    // ---- split-K finish: last block of the 4 splits combines this q-tile ----
    __threadfence();                          // release our opart/lpart stores
    __syncthreads();                          // all threads' fences done
    if (tid == 0) {
        int old = atomicAdd(&counters[b * 32 + qtile], 1);
        lastflag = (old == NSPLIT - 1);
    }
    __syncthreads();
    if (lastflag) {
        __threadfence();                      // acquire the other splits' stores
        const float gamma = gamma_p[0];
        const int rr = tid >> 5;              // 0..15 rows per pass
        const int cc = (tid & 31) * 8;        // 8 cols per thread
        #pragma unroll
        for (int it = 0; it < 8; ++it) {
            const size_t grow = (size_t)b * 4096 + q0 + it * 16 + rr;
            float suml = (lpart[grow] + lpart[16384 + grow]) +
                         (lpart[2 * 16384 + grow] + lpart[3 * 16384 + grow]);
            const float inv = gamma * frcp(suml);
            float sumO[8];
            #pragma unroll
            for (int jj = 0; jj < 8; ++jj) sumO[jj] = 0.f;
            #pragma unroll
            for (int s = 0; s < NSPLIT; ++s) {
                bf16x8 o = *(const bf16x8*)(opart + ((size_t)(s * 16384) + grow) * 256 + cc);
                #pragma unroll
                for (int jj = 0; jj < 8; ++jj) sumO[jj] += bf2f((unsigned short)o[jj]);
            }
            const size_t base = grow * 256 + cc;
            float4 x0 = *(const float4*)(x + base);
            float4 x1 = *(const float4*)(x + base + 4);
            float4 o0, o1;
            o0.x = sumO[0] * inv + x0.x; o0.y = sumO[1] * inv + x0.y;
            o0.z = sumO[2] * inv + x0.z; o0.w = sumO[3] * inv + x0.w;
            o1.x = sumO[4] * inv + x1.x; o1.y = sumO[5] * inv + x1.y;
            o1.z = sumO[6] * inv + x1.z; o1.w = sumO[7] * inv + x1.w;
            *(float4*)(out + base)     = o0;
            *(float4*)(out + base + 4) = o1;
        }
    }
}

extern "C" void kernel_launch(void* const* d_in, const int* in_sizes, int n_in,
                              void* d_out, int out_size, void* d_ws, size_t ws_size,
                              hipStream_t stream) {
    const float* x     = (const float*)d_in[0];
    const float* wq    = (const float*)d_in[1];
    const float* bq    = (const float*)d_in[2];
    const float* wk    = (const float*)d_in[3];
    const float* bk    = (const float*)d_in[4];
    const float* wv    = (const float*)d_in[5];
    const float* bv    = (const float*)d_in[6];
    const float* gamma = (const float*)d_in[7];
    float* out = (float*)d_out;

    char* ws = (char*)d_ws;
    unsigned short* wt    = (unsigned short*)(ws);                  // 160KB
    unsigned short* q_ws  = (unsigned short*)(ws + 163840);         // 1MB
    unsigned short* k_ws  = (unsigned short*)(ws + 1212416);        // 1MB
    unsigned short* vt_ws = (unsigned short*)(ws + 2260992);        // 8MB
    unsigned short* opart = (unsigned short*)(ws + 10649600);       // 32MB
    float*          lpart = (float*)(ws + 44204032);                // 256KB
    int*            ctrs  = (int*)(ws + 44466176);                  // 512B

    wt_kernel  <<<320,  256, 0, stream>>>(wq, wk, wv, wt, ctrs);
    proj_kernel<<<1024, 256, 0, stream>>>(x, wt, bq, bk, bv, q_ws, k_ws, vt_ws);
    attn_kernel<<<512,  512, 0, stream>>>(q_ws, k_ws, vt_ws, opart, lpart,
                                          x, gamma, out, ctrs);
}

// Round 18
// 102.923 us; speedup vs baseline: 2.9844x; 2.9844x over previous
//
#include <hip/hip_runtime.h>
#include <hip/hip_bf16.h>

typedef __attribute__((ext_vector_type(8))) short bf16x8;
typedef __attribute__((ext_vector_type(4))) float f32x4;
typedef __attribute__((ext_vector_type(16))) float f32x16;
typedef __attribute__((ext_vector_type(4))) int int4v;

// Problem constants
#define NB 4
#define NN 4096
#define NC 256
#define NSPLIT 4
#define KEYS_PER_SPLIT 1024
#define KT_ITERS 16      // KEYS_PER_SPLIT / 64
#define LOG2E 1.4426950408889634f

__device__ __forceinline__ unsigned short f2bf(float f) {
    unsigned u = __builtin_bit_cast(unsigned, f);
    u += 0x7fffu + ((u >> 16) & 1u);   // round-to-nearest-even
    return (unsigned short)(u >> 16);
}
__device__ __forceinline__ float bf2f(unsigned short u) {
    unsigned v = ((unsigned)u) << 16;
    return __builtin_bit_cast(float, v);
}
__device__ __forceinline__ void load_lds16(const void* g, void* l) {
    __builtin_amdgcn_global_load_lds(
        (const __attribute__((address_space(1))) void*)g,
        (__attribute__((address_space(3))) void*)l, 16, 0, 0);
}
__device__ __forceinline__ unsigned cvtpk(float lo, float hi) {
    unsigned d;
    asm("v_cvt_pk_bf16_f32 %0, %1, %2" : "=v"(d) : "v"(lo), "v"(hi));
    return d;
}
__device__ __forceinline__ void pl32swap(unsigned &a, unsigned &b) {
    asm volatile("v_permlane32_swap_b32 %0, %1" : "+v"(a), "+v"(b));
}
__device__ __forceinline__ float fexp2(float x) {
    float r;
    asm("v_exp_f32 %0, %1" : "=v"(r) : "v"(x));
    return r;
}
__device__ __forceinline__ float frcp(float x) {
    float r;
    asm("v_rcp_f32 %0, %1" : "=v"(r) : "v"(x));
    return r;
}

// ---------------- kernel 0: weight transpose + bf16 cast ----------------
// wk is pre-scaled by log2(e) so attention can use v_exp_f32 (2^x) directly.
__global__ __launch_bounds__(256) void wt_kernel(
    const float* __restrict__ wq, const float* __restrict__ wk,
    const float* __restrict__ wv, unsigned short* __restrict__ wt)
{
    const int c = blockIdx.x;     // 0..319
    const int k = threadIdx.x;    // 0..255
    float v;
    if (c < 32)      v = wq[k * 32 + c];
    else if (c < 64) v = wk[k * 32 + (c - 32)] * LOG2E;
    else             v = wv[k * 256 + (c - 64)];
    wt[c * 256 + k] = f2bf(v);
}

// ---------------- kernel 1: QKV projection (MFMA, no LDS) ----------------
// XCD-affinity remap: XCD x owns contiguous rows [x*2048, (x+1)*2048) so its
// vt/q/k writes are XCD-contiguous full L2 lines (and attn can read them back
// from the same XCD's L2).
__global__ __launch_bounds__(256) void proj_kernel(
    const float* __restrict__ x,              // [16384][256]
    const unsigned short* __restrict__ wt,    // [320][256] = W^T bf16
    const float* __restrict__ bq, const float* __restrict__ bk,
    const float* __restrict__ bv,
    unsigned short* __restrict__ q_ws,
    unsigned short* __restrict__ k_ws,
    unsigned short* __restrict__ vt_ws)
{
    const int lane = threadIdx.x & 63;
    const int w    = threadIdx.x >> 6;
    const int l15  = lane & 15, hh = lane >> 4;
    // blockIdx%8 = XCD (dispatch round-robin); give XCD x logical blocks x*128..+127
    const int lb   = (blockIdx.x >> 3) + (blockIdx.x & 7) * 128;
    const int m0   = lb * 16;              // 16 rows per block
    const int ct0  = w * 5;                // this wave's 5 col-groups

    f32x4 acc[5];
    #pragma unroll
    for (int i = 0; i < 5; ++i) acc[i] = f32x4{0.f, 0.f, 0.f, 0.f};

    const float* xrow = x + (size_t)(m0 + l15) * 256 + hh * 8;
    #pragma unroll
    for (int ks = 0; ks < 8; ++ks) {
        float4 xa = ((const float4*)(xrow + ks * 32))[0];
        float4 xb = ((const float4*)(xrow + ks * 32))[1];
        bf16x8 afrag;
        afrag[0] = (short)f2bf(xa.x); afrag[1] = (short)f2bf(xa.y);
        afrag[2] = (short)f2bf(xa.z); afrag[3] = (short)f2bf(xa.w);
        afrag[4] = (short)f2bf(xb.x); afrag[5] = (short)f2bf(xb.y);
        afrag[6] = (short)f2bf(xb.z); afrag[7] = (short)f2bf(xb.w);
        #pragma unroll
        for (int c = 0; c < 5; ++c) {
            bf16x8 bfrag = *(const bf16x8*)(wt + (size_t)((ct0 + c) * 16 + l15) * 256 + ks * 32 + hh * 8);
            acc[c] = __builtin_amdgcn_mfma_f32_16x16x32_bf16(afrag, bfrag, acc[c], 0, 0, 0);
        }
    }

    const int b    = m0 >> 12;
    const int nloc = m0 & 4095;
    #pragma unroll
    for (int c = 0; c < 5; ++c) {
        const int ct = ct0 + c;
        const int c0 = ct * 16;
        float bias;
        if (c0 < 32)      bias = bq[c0 + l15];
        else if (c0 < 64) bias = bk[c0 - 32 + l15] * LOG2E;
        else              bias = bv[c0 - 64 + l15];
        if (c0 < 64) {
            unsigned short* dst = (c0 < 32) ? q_ws : k_ws;
            const int cc = (c0 < 32) ? c0 : (c0 - 32);
            #pragma unroll
            for (int i = 0; i < 4; ++i)
                dst[(size_t)(m0 + hh * 4 + i) * 32 + cc + l15] = f2bf(acc[c][i] + bias);
        } else {
            const int cc = c0 - 64 + l15;
            #pragma unroll
            for (int i = 0; i < 4; i += 2) {
                unsigned lo = f2bf(acc[c][i]     + bias);
                unsigned hi = f2bf(acc[c][i + 1] + bias);
                *(unsigned*)(vt_ws + ((size_t)b * 256 + cc) * 4096 + nloc + hh * 4 + i)
                    = lo | (hi << 16);
            }
        }
    }
}

// ---------------- kernel 2: flash attention, P in regs + V dbuf ----------------
// EXACT R14 loop (65.3us proven). XCD-affinity: b = xcd>>1, split = (xcd&1)*2
// + (j>>5) so this block's V/K reads come from the SAME XCD's L2 that proj
// wrote (vt rows for (b, key-half) were produced by exactly that XCD).
__global__ __launch_bounds__(512, 4) void attn_kernel(
    const unsigned short* __restrict__ q_ws,
    const unsigned short* __restrict__ k_ws,
    const unsigned short* __restrict__ vt_ws,
    unsigned short* __restrict__ opart,   // [4][16384][256] bf16 (unnormalized)
    float* __restrict__ lpart)            // [4][16384] f32
{
    __shared__ unsigned short vt_lds[2 * 256 * 64];  // 64 KB, two 32KB buffers

    const int tid  = threadIdx.x;
    const int lane = tid & 63;
    const int wid  = tid >> 6;     // 0..7
    const int l31  = lane & 31;
    const int hi   = lane >> 5;
    const int wr   = wid >> 1;             // q group (32 rows), 0..3
    const int wc   = wid & 1;              // col half (128 cols)

    // XCD-affinity decomposition (matches proj's writer XCD for V/K)
    const int xcd   = blockIdx.x & 7;
    const int j     = blockIdx.x >> 3;          // 0..63
    const int qtile = j & 31;
    const int b     = xcd >> 1;
    const int split = (xcd & 1) * 2 + (j >> 5);
    const int q0    = qtile * 128;
    const int key0  = split * KEYS_PER_SPLIT;

    // persistent Q B-frags
    bf16x8 aq[2];
    #pragma unroll
    for (int cs = 0; cs < 2; ++cs)
        aq[cs] = *(const bf16x8*)(q_ws +
            (size_t)(b * 4096 + q0 + wr * 32 + l31) * 32 + cs * 16 + hi * 8);

    f32x16 acc[4];
    #pragma unroll
    for (int ct = 0; ct < 4; ++ct)
        #pragma unroll
        for (int r = 0; r < 16; ++r) acc[ct][r] = 0.f;
    float lsum = 0.f;

    const unsigned short* vt_base = vt_ws + (size_t)b * 256 * 4096;
    const unsigned short* k_base  = k_ws + (size_t)b * 4096 * 32;

    // ---- prologue: stage tile 0 into buffer 0 ----
    #pragma unroll
    for (int e = 0; e < 4; ++e) {
        int idx  = e * 512 + tid;
        int c    = idx >> 3;
        int slot = idx & 7;
        const unsigned short* src = vt_base + (size_t)c * 4096 + key0 + ((slot ^ (c & 7)) << 3);
        load_lds16(src, (char*)vt_lds + idx * 16);
    }

    for (int kt = 0; kt < KT_ITERS; ++kt) {
        const int kb      = key0 + kt * 64;
        const int cur_off = (kt & 1) << 15;     // byte offset of current V buffer

        // single barrier: STAGE(kt) drained+visible; PV(kt-1) done with other buf
        __syncthreads();

        // ---- prefetch STAGE(kt+1) into the other buffer ----
        if (kt + 1 < KT_ITERS) {
            const int nxt_off = cur_off ^ 32768;
            #pragma unroll
            for (int e = 0; e < 4; ++e) {
                int idx  = e * 512 + tid;
                int c    = idx >> 3;
                int slot = idx & 7;
                const unsigned short* src = vt_base + (size_t)c * 4096 + (kb + 64) + ((slot ^ (c & 7)) << 3);
                load_lds16(src, (char*)vt_lds + nxt_off + idx * 16);
            }
        }

        // ---- swapped QK per 32-key tile + exp2 + in-register P assembly ----
        unsigned pa[4][4];   // [kstep16][dword]
        #pragma unroll
        for (int ktile = 0; ktile < 2; ++ktile) {
            bf16x8 ak0 = *(const bf16x8*)(k_base +
                (size_t)(kb + ktile * 32 + l31) * 32 + hi * 8);
            bf16x8 ak1 = *(const bf16x8*)(k_base +
                (size_t)(kb + ktile * 32 + l31) * 32 + 16 + hi * 8);
            f32x16 e0;
            #pragma unroll
            for (int r = 0; r < 16; ++r) e0[r] = 0.f;
            e0 = __builtin_amdgcn_mfma_f32_32x32x16_bf16(ak0, aq[0], e0, 0, 0, 0);
            e0 = __builtin_amdgcn_mfma_f32_32x32x16_bf16(ak1, aq[1], e0, 0, 0, 0);

            float s = 0.f;
            #pragma unroll
            for (int h = 0; h < 2; ++h) {
                float p0 = fexp2(e0[h*8+0]), p1 = fexp2(e0[h*8+1]);
                float p2 = fexp2(e0[h*8+2]), p3 = fexp2(e0[h*8+3]);
                float p4 = fexp2(e0[h*8+4]), p5 = fexp2(e0[h*8+5]);
                float p6 = fexp2(e0[h*8+6]), p7 = fexp2(e0[h*8+7]);
                s += ((p0 + p1) + (p2 + p3)) + ((p4 + p5) + (p6 + p7));
                unsigned d0 = cvtpk(p0, p1);
                unsigned d1 = cvtpk(p2, p3);
                unsigned d2 = cvtpk(p4, p5);
                unsigned d3 = cvtpk(p6, p7);
                pl32swap(d0, d2);
                pl32swap(d1, d3);
                const int ks = ktile * 2 + h;
                pa[ks][0] = d0; pa[ks][1] = d1;
                pa[ks][2] = d2; pa[ks][3] = d3;
            }
            lsum += s;
        }

        // ---- PV from current buffer (staged last iter, drained at barrier) ----
        __builtin_amdgcn_s_setprio(1);
        #pragma unroll
        for (int ks = 0; ks < 4; ++ks) {
            union { unsigned u[4]; bf16x8 v; } cvt;
            cvt.u[0] = pa[ks][0]; cvt.u[1] = pa[ks][1];
            cvt.u[2] = pa[ks][2]; cvt.u[3] = pa[ks][3];
            #pragma unroll
            for (int ct = 0; ct < 4; ++ct) {
                int c = wc * 128 + ct * 32 + l31;
                int chunk = ks * 2 + hi;
                bf16x8 bvf = *(const bf16x8*)((char*)vt_lds + cur_off + c * 128 + ((chunk ^ (c & 7)) << 4));
                acc[ct] = __builtin_amdgcn_mfma_f32_32x32x16_bf16(cvt.v, bvf, acc[ct], 0, 0, 0);
            }
        }
        __builtin_amdgcn_s_setprio(0);
    }

    // ---- l totals (keys split across hi halves only) ----
    lsum += __shfl_xor(lsum, 32);

    const size_t rowb = (size_t)(split * 4 + b) * 4096 + q0 + wr * 32;
    if (wc == 0 && hi == 0)
        lpart[rowb + l31] = lsum;

    // ---- epilogue: direct scalar stores (conflict-free, proven R3/R5/R9) ----
    #pragma unroll
    for (int ct = 0; ct < 4; ++ct) {
        int col = wc * 128 + ct * 32 + l31;
        #pragma unroll
        for (int rr = 0; rr < 16; ++rr) {
            int row = (rr & 3) + 8 * (rr >> 2) + 4 * hi;
            opart[(rowb + row) * 256 + col] = f2bf(acc[ct][rr]);
        }
    }
}

// ---------------- kernel 3: combine splits + residual ----------------
// XCD-affinity remap: XCD x handles contiguous rows [x*2048, (x+1)*2048) ->
// half the opart reads hit the local L2 that attn dirtied.
__global__ __launch_bounds__(256) void combine_kernel(
    const unsigned short* __restrict__ opart,   // [4][16384][256]
    const float* __restrict__ lpart,            // [4][16384]
    const float* __restrict__ x,
    const float* __restrict__ gamma_p,
    float* __restrict__ out)
{
    const int lb = (blockIdx.x >> 3) + (blockIdx.x & 7) * 256;
    const int t  = lb * 256 + threadIdx.x;           // 0..524287
    const int r  = t >> 5;                           // global row 0..16383
    const int c0 = (t & 31) * 8;
    const float gamma = gamma_p[0];

    // l-sum first so rcp overlaps the opart loads
    float suml = (lpart[r] + lpart[16384 + r]) +
                 (lpart[2 * 16384 + r] + lpart[3 * 16384 + r]);
    const float inv = gamma * frcp(suml);

    float sumO[8];
    #pragma unroll
    for (int j = 0; j < 8; ++j) sumO[j] = 0.f;
    #pragma unroll
    for (int s = 0; s < NSPLIT; ++s) {
        bf16x8 o = *(const bf16x8*)(opart + ((size_t)(s * 16384 + r)) * 256 + c0);
        #pragma unroll
        for (int j = 0; j < 8; ++j) sumO[j] += bf2f((unsigned short)o[j]);
    }
    const size_t base = (size_t)r * 256 + c0;
    float4 x0 = *(const float4*)(x + base);
    float4 x1 = *(const float4*)(x + base + 4);
    float4 o0, o1;
    o0.x = sumO[0] * inv + x0.x; o0.y = sumO[1] * inv + x0.y;
    o0.z = sumO[2] * inv + x0.z; o0.w = sumO[3] * inv + x0.w;
    o1.x = sumO[4] * inv + x1.x; o1.y = sumO[5] * inv + x1.y;
    o1.z = sumO[6] * inv + x1.z; o1.w = sumO[7] * inv + x1.w;
    *(float4*)(out + base)     = o0;
    *(float4*)(out + base + 4) = o1;
}

extern "C" void kernel_launch(void* const* d_in, const int* in_sizes, int n_in,
                              void* d_out, int out_size, void* d_ws, size_t ws_size,
                              hipStream_t stream) {
    const float* x     = (const float*)d_in[0];
    const float* wq    = (const float*)d_in[1];
    const float* bq    = (const float*)d_in[2];
    const float* wk    = (const float*)d_in[3];
    const float* bk    = (const float*)d_in[4];
    const float* wv    = (const float*)d_in[5];
    const float* bv    = (const float*)d_in[6];
    const float* gamma = (const float*)d_in[7];
    float* out = (float*)d_out;

    char* ws = (char*)d_ws;
    unsigned short* wt    = (unsigned short*)(ws);                  // 160KB
    unsigned short* q_ws  = (unsigned short*)(ws + 163840);         // 1MB
    unsigned short* k_ws  = (unsigned short*)(ws + 1212416);        // 1MB
    unsigned short* vt_ws = (unsigned short*)(ws + 2260992);        // 8MB
    unsigned short* opart = (unsigned short*)(ws + 10649600);       // 32MB
    float*          lpart = (float*)(ws + 44204032);                // 256KB

    wt_kernel     <<<320,  256, 0, stream>>>(wq, wk, wv, wt);
    proj_kernel   <<<1024, 256, 0, stream>>>(x, wt, bq, bk, bv, q_ws, k_ws, vt_ws);
    attn_kernel   <<<512,  512, 0, stream>>>(q_ws, k_ws, vt_ws, opart, lpart);
    combine_kernel<<<2048, 256, 0, stream>>>(opart, lpart, x, gamma, out);
}